// Round 1
// baseline (527.084 us; speedup 1.0000x reference)
//
#include <hip/hip_runtime.h>
#include <math.h>

#define S_LEN 1024
#define BATCH 32
#define EMB   128
#define NHEAD 4
#define HDIM  32
// q/k/v each: B*H*S*D = 32*4*1024*32 floats
#define HEADBUF 4194304

// ---------------- Kernel 1: QKV projection ----------------
// qkv[t][f] = sum_e x[t][e]*W[f][e] + b[f]  -> stored (B,H,S,D) per q/k/v
// grid (2048, 6), block 256. blockIdx.y = 64-row chunk of W (6*64 = 384).
__global__ __launch_bounds__(256)
void qkv_kernel(const float* __restrict__ x, const float* __restrict__ w,
                const float* __restrict__ bias, float* __restrict__ qkv)
{
    __shared__ float xs[16][132];
    __shared__ float wsh[64][132];
    const int tid   = threadIdx.x;
    const int tile  = blockIdx.x;
    const int fbase = blockIdx.y * 64;

    const float4* xg = (const float4*)(x + (size_t)tile * (16 * EMB));
    #pragma unroll
    for (int j = 0; j < 2; ++j) {
        int idx = tid + j * 256;            // 0..511
        float4 v = xg[idx];
        int tok = idx >> 5, k4 = idx & 31;
        *(float4*)&xs[tok][k4 * 4] = v;
    }
    const float4* wg = (const float4*)(w + (size_t)fbase * EMB);
    #pragma unroll
    for (int j = 0; j < 8; ++j) {
        int idx = tid + j * 256;            // 0..2047
        float4 v = wg[idx];
        int f = idx >> 5, k4 = idx & 31;
        *(float4*)&wsh[f][k4 * 4] = v;
    }
    __syncthreads();

    const int tok  = tid >> 4;   // 0..15
    const int fgrp = tid & 15;   // 0..15
    float acc[4] = {0.f, 0.f, 0.f, 0.f};
    #pragma unroll
    for (int k4 = 0; k4 < 32; ++k4) {
        float4 a = *(const float4*)&xs[tok][k4 * 4];
        #pragma unroll
        for (int c = 0; c < 4; ++c) {
            float4 b = *(const float4*)&wsh[fgrp + 16 * c][k4 * 4];
            acc[c] = fmaf(a.x, b.x, acc[c]);
            acc[c] = fmaf(a.y, b.y, acc[c]);
            acc[c] = fmaf(a.z, b.z, acc[c]);
            acc[c] = fmaf(a.w, b.w, acc[c]);
        }
    }
    const int t = tile * 16 + tok;
    const int s = t >> 5;                   // t / BATCH
    const int b = t & 31;
    #pragma unroll
    for (int c = 0; c < 4; ++c) {
        int fl = fgrp + 16 * c;             // 0..63
        int fg = fbase + fl;                // 0..383
        float val = acc[c] + bias[fg];
        int which = fg >> 7;                // 0=q 1=k 2=v
        int r = fg & 127;
        int h = r >> 5, d = r & 31;
        qkv[(size_t)which * HEADBUF +
            (((size_t)(b * NHEAD + h) * S_LEN + s) * HDIM) + d] = val;
    }
}

// ---------------- Kernel 2: flash attention (fp32) ----------------
// grid (B*H = 128, S/64 = 16), block 256. Output written as (S,B,E) into d_out.
__global__ __launch_bounds__(256)
void attn_kernel(const float* __restrict__ qg, const float* __restrict__ kg,
                 const float* __restrict__ vg, float* __restrict__ attn)
{
    __shared__ float Kt[64][36];
    __shared__ float Vt[64][36];
    __shared__ float Ps[64][65];

    const int tid  = threadIdx.x;
    const int bh   = blockIdx.x;            // b*NHEAD + h
    const int qt   = blockIdx.y;
    const int qi   = tid >> 2;              // query row 0..63
    const int kgrp = tid & 3;               // key group / d group
    const int d0   = kgrp * 8;

    const float* qp = qg + (size_t)bh * (S_LEN * HDIM) + qt * (64 * HDIM);
    const float* kp = kg + (size_t)bh * (S_LEN * HDIM);
    const float* vp = vg + (size_t)bh * (S_LEN * HDIM);

    float4 q4[8];
    const float4* qr = (const float4*)(qp + qi * HDIM);
    #pragma unroll
    for (int j = 0; j < 8; ++j) q4[j] = qr[j];

    float m = -INFINITY, l = 0.f;
    float o[8];
    #pragma unroll
    for (int j = 0; j < 8; ++j) o[j] = 0.f;

    const float scale = 0.17677669529663687f;   // 1/sqrt(32)

    for (int kt = 0; kt < 16; ++kt) {
        __syncthreads();
        const float4* ksrc = (const float4*)(kp + kt * (64 * HDIM));
        const float4* vsrc = (const float4*)(vp + kt * (64 * HDIM));
        #pragma unroll
        for (int j = 0; j < 2; ++j) {
            int idx = tid + j * 256;        // 0..511
            int r = idx >> 3, c4 = idx & 7;
            *(float4*)&Kt[r][c4 * 4] = ksrc[idx];
            *(float4*)&Vt[r][c4 * 4] = vsrc[idx];
        }
        __syncthreads();

        float sc[16];
        float lm = -INFINITY;
        #pragma unroll
        for (int kk = 0; kk < 16; ++kk) {
            int kr = kgrp + kk * 4;         // interleaved keys: bank-spread
            float a = 0.f;
            #pragma unroll
            for (int d4 = 0; d4 < 8; ++d4) {
                float4 kv = *(const float4*)&Kt[kr][d4 * 4];
                a = fmaf(q4[d4].x, kv.x, a);
                a = fmaf(q4[d4].y, kv.y, a);
                a = fmaf(q4[d4].z, kv.z, a);
                a = fmaf(q4[d4].w, kv.w, a);
            }
            a *= scale;
            sc[kk] = a;
            lm = fmaxf(lm, a);
        }
        lm = fmaxf(lm, __shfl_xor(lm, 1));
        lm = fmaxf(lm, __shfl_xor(lm, 2));
        const float mnew  = fmaxf(m, lm);
        const float alpha = __expf(m - mnew);
        float ls = 0.f;
        #pragma unroll
        for (int kk = 0; kk < 16; ++kk) {
            float p = __expf(sc[kk] - mnew);
            Ps[qi][kgrp + kk * 4] = p;
            ls += p;
        }
        ls += __shfl_xor(ls, 1);
        ls += __shfl_xor(ls, 2);
        l = l * alpha + ls;
        m = mnew;
        #pragma unroll
        for (int j = 0; j < 8; ++j) o[j] *= alpha;
        __syncthreads();

        #pragma unroll 8
        for (int kk = 0; kk < 64; ++kk) {
            float p = Ps[qi][kk];
            float4 v0 = *(const float4*)&Vt[kk][d0];
            float4 v1 = *(const float4*)&Vt[kk][d0 + 4];
            o[0] = fmaf(p, v0.x, o[0]);
            o[1] = fmaf(p, v0.y, o[1]);
            o[2] = fmaf(p, v0.z, o[2]);
            o[3] = fmaf(p, v0.w, o[3]);
            o[4] = fmaf(p, v1.x, o[4]);
            o[5] = fmaf(p, v1.y, o[5]);
            o[6] = fmaf(p, v1.z, o[6]);
            o[7] = fmaf(p, v1.w, o[7]);
        }
    }
    const float inv = 1.f / l;
    const int s = qt * 64 + qi;
    const int b = bh >> 2, h = bh & 3;
    float* op = attn + ((size_t)s * BATCH + b) * EMB + h * HDIM + d0;
    float4 r0, r1;
    r0.x = o[0] * inv; r0.y = o[1] * inv; r0.z = o[2] * inv; r0.w = o[3] * inv;
    r1.x = o[4] * inv; r1.y = o[5] * inv; r1.z = o[6] * inv; r1.w = o[7] * inv;
    *(float4*)op       = r0;
    *(float4*)(op + 4) = r1;
}

// ---------------- Kernel 3: out_proj + bias + residual + LayerNorm ----------
// grid 4096, block 256. `out` holds attn (S,B,E) on entry; overwritten with
// the final result. Safe: each block reads only its own 8 token rows (staged
// to LDS before any write).
__global__ __launch_bounds__(256)
void proj_ln_kernel(const float* __restrict__ x, const float* __restrict__ wo,
                    const float* __restrict__ bo, const float* __restrict__ gm,
                    const float* __restrict__ bt, float* out)
{
    __shared__ float as[8][132];
    __shared__ float wsh[64][132];
    const int tid  = threadIdx.x;
    const int tile = blockIdx.x;

    {
        const float4* ag = (const float4*)(out + (size_t)tile * (8 * EMB));
        int idx = tid;                      // 0..255 (= 8*128/4)
        float4 v = ag[idx];
        int tok = idx >> 5, k4 = idx & 31;
        *(float4*)&as[tok][k4 * 4] = v;
    }

    const float4* wg = (const float4*)wo;
    const int tok  = tid >> 5;   // 0..7
    const int fgrp = tid & 31;   // 0..31
    float acc[4];

    for (int half = 0; half < 2; ++half) {
        if (half) __syncthreads();          // prev compute done before overwrite
        #pragma unroll
        for (int j = 0; j < 8; ++j) {
            int idx = tid + j * 256;        // 0..2047
            float4 v = wg[half * 2048 + idx];
            int f = idx >> 5, k4 = idx & 31;
            *(float4*)&wsh[f][k4 * 4] = v;
        }
        __syncthreads();
        acc[half * 2 + 0] = 0.f;
        acc[half * 2 + 1] = 0.f;
        #pragma unroll
        for (int k4 = 0; k4 < 32; ++k4) {
            float4 a = *(const float4*)&as[tok][k4 * 4];
            #pragma unroll
            for (int c = 0; c < 2; ++c) {
                float4 b = *(const float4*)&wsh[fgrp + 32 * c][k4 * 4];
                int i = half * 2 + c;
                acc[i] = fmaf(a.x, b.x, acc[i]);
                acc[i] = fmaf(a.y, b.y, acc[i]);
                acc[i] = fmaf(a.z, b.z, acc[i]);
                acc[i] = fmaf(a.w, b.w, acc[i]);
            }
        }
    }
    // acc[i] corresponds to f = fgrp + 32*i
    const int t = tile * 8 + tok;
    float vals[4];
    float sum = 0.f, sq = 0.f;
    #pragma unroll
    for (int i = 0; i < 4; ++i) {
        int f = fgrp + 32 * i;
        float v = acc[i] + bo[f] + x[(size_t)t * EMB + f];
        vals[i] = v;
        sum += v;
        sq = fmaf(v, v, sq);
    }
    #pragma unroll
    for (int sft = 1; sft < 32; sft <<= 1) {
        sum += __shfl_xor(sum, sft);
        sq  += __shfl_xor(sq, sft);
    }
    const float mean = sum * (1.f / 128.f);
    const float var  = sq * (1.f / 128.f) - mean * mean;
    const float rstd = rsqrtf(var + 1e-5f);
    #pragma unroll
    for (int i = 0; i < 4; ++i) {
        int f = fgrp + 32 * i;
        out[(size_t)t * EMB + f] = (vals[i] - mean) * rstd * gm[f] + bt[f];
    }
}

extern "C" void kernel_launch(void* const* d_in, const int* in_sizes, int n_in,
                              void* d_out, int out_size, void* d_ws, size_t ws_size,
                              hipStream_t stream) {
    const float* x     = (const float*)d_in[0];
    const float* wi    = (const float*)d_in[1];
    const float* bi    = (const float*)d_in[2];
    const float* wo    = (const float*)d_in[3];
    const float* bo    = (const float*)d_in[4];
    const float* gamma = (const float*)d_in[5];
    const float* beta  = (const float*)d_in[6];
    float* out = (float*)d_out;
    float* ws  = (float*)d_ws;    // needs 3*4194304 floats = 50.3 MB
    const float* q = ws;
    const float* k = ws + HEADBUF;
    const float* v = ws + 2 * (size_t)HEADBUF;

    qkv_kernel<<<dim3(2048, 6), 256, 0, stream>>>(x, wi, bi, ws);
    attn_kernel<<<dim3(128, 16), 256, 0, stream>>>(q, k, v, out);
    proj_ln_kernel<<<4096, 256, 0, stream>>>(x, wo, bo, gamma, beta, out);
}

// Round 3
// 301.342 us; speedup vs baseline: 1.7491x; 1.7491x over previous
//
#include <hip/hip_runtime.h>
#include <hip/hip_bf16.h>
#include <math.h>

#define S_LEN 1024
#define BATCH 32
#define EMB   128
#define NHEAD 4
#define HDIM  32
#define BHN   (BATCH*NHEAD)          // 128
#define HBUF  (BHN*S_LEN*HDIM)       // 4194304 elements per q/k/v (bf16)

typedef __attribute__((ext_vector_type(4))) float f32x4;
typedef __attribute__((ext_vector_type(8))) short bf16x8;
typedef __attribute__((ext_vector_type(4))) short bf16x4;

// (1/sqrt(32)) * log2(e): folded into q at store so softmax is pure exp2
#define Q_PRESCALE 0.25503588f

__device__ __forceinline__ unsigned short f2bf(float f) {
    union { float f; unsigned u; } v; v.f = f;
    unsigned r = v.u + 0x7fff + ((v.u >> 16) & 1);   // RNE
    return (unsigned short)(r >> 16);
}

__device__ __forceinline__ void gl_lds16(const void* g, void* l) {
    __builtin_amdgcn_global_load_lds(
        (const __attribute__((address_space(1))) unsigned*)g,
        (__attribute__((address_space(3))) unsigned*)l, 16, 0, 0);
}

// ---------------- Kernel 1: QKV projection (fp32 compute, bf16 out) --------
// q: (B,H,S,D) bf16 prescaled; k: (B,H,S,D) bf16; v: (B,H,D,S) bf16 (transposed)
__global__ __launch_bounds__(256)
void qkv_kernel(const float* __restrict__ x, const float* __restrict__ w,
                const float* __restrict__ bias,
                __hip_bfloat16* __restrict__ qb,
                __hip_bfloat16* __restrict__ kb,
                __hip_bfloat16* __restrict__ vtb)
{
    __shared__ float xs[16][132];
    __shared__ float wsh[64][132];
    const int tid   = threadIdx.x;
    const int tile  = blockIdx.x;
    const int fbase = blockIdx.y * 64;

    const float4* xg = (const float4*)(x + (size_t)tile * (16 * EMB));
    #pragma unroll
    for (int j = 0; j < 2; ++j) {
        int idx = tid + j * 256;
        float4 v = xg[idx];
        int tok = idx >> 5, k4 = idx & 31;
        *(float4*)&xs[tok][k4 * 4] = v;
    }
    const float4* wg = (const float4*)(w + (size_t)fbase * EMB);
    #pragma unroll
    for (int j = 0; j < 8; ++j) {
        int idx = tid + j * 256;
        float4 v = wg[idx];
        int f = idx >> 5, k4 = idx & 31;
        *(float4*)&wsh[f][k4 * 4] = v;
    }
    __syncthreads();

    const int tok  = tid >> 4;
    const int fgrp = tid & 15;
    float acc[4] = {0.f, 0.f, 0.f, 0.f};
    #pragma unroll
    for (int k4 = 0; k4 < 32; ++k4) {
        float4 a = *(const float4*)&xs[tok][k4 * 4];
        #pragma unroll
        for (int c = 0; c < 4; ++c) {
            float4 b = *(const float4*)&wsh[fgrp + 16 * c][k4 * 4];
            acc[c] = fmaf(a.x, b.x, acc[c]);
            acc[c] = fmaf(a.y, b.y, acc[c]);
            acc[c] = fmaf(a.z, b.z, acc[c]);
            acc[c] = fmaf(a.w, b.w, acc[c]);
        }
    }
    const int t = tile * 16 + tok;
    const int s = t >> 5;
    const int b = t & 31;
    #pragma unroll
    for (int c = 0; c < 4; ++c) {
        int fg = fbase + fgrp + 16 * c;
        float val = acc[c] + bias[fg];
        int which = fg >> 7;
        int r = fg & 127;
        int h = r >> 5, d = r & 31;
        int bh = b * NHEAD + h;
        if (which == 0) {
            qb[(size_t)bh * (S_LEN * HDIM) + s * HDIM + d] =
                __float2bfloat16(val * Q_PRESCALE);
        } else if (which == 1) {
            kb[(size_t)bh * (S_LEN * HDIM) + s * HDIM + d] =
                __float2bfloat16(val);
        } else {
            vtb[(size_t)bh * (HDIM * S_LEN) + (size_t)d * S_LEN + s] =
                __float2bfloat16(val);
        }
    }
}

// ---------------- Kernel 2: flash attention, bf16 MFMA ----------------
// grid (BH=128, S/64=16), block 256 (4 waves, 16 queries/wave).
// Swapped QK^T: mfma(K, Q) -> lane holds 16 scores for ONE query row.
__global__ __launch_bounds__(256)
void attn_kernel(const __hip_bfloat16* __restrict__ qg,
                 const __hip_bfloat16* __restrict__ kg,
                 const __hip_bfloat16* __restrict__ vtg,
                 float* __restrict__ attn)
{
    __shared__ __hip_bfloat16 Kl[2][64 * 32];   // [key][d] linear
    __shared__ __hip_bfloat16 Vl[2][32 * 64];   // [d][key] linear (Vt)
    __shared__ __hip_bfloat16 Pl[4][16 * 72];   // per-wave P, pitch 72 bf16

    const int tid = threadIdx.x;
    const int w   = tid >> 6;
    const int l   = tid & 63;
    const int q15 = l & 15;
    const int g   = l >> 4;
    const int bh  = blockIdx.x;
    const int qt  = blockIdx.y;

    const __hip_bfloat16* kp  = kg  + (size_t)bh * (S_LEN * HDIM);
    const __hip_bfloat16* vtp = vtg + (size_t)bh * (HDIM * S_LEN);

    // Q fragment (B operand): lane(q15,g) holds Q[qrow][8g..8g+7]
    bf16x8 qf = *(const bf16x8*)(qg + (size_t)bh * (S_LEN * HDIM)
                                 + (size_t)(qt * 64 + w * 16 + q15) * HDIM + 8 * g);

    f32x4 acc0 = {0.f, 0.f, 0.f, 0.f};
    f32x4 acc1 = {0.f, 0.f, 0.f, 0.f};
    float mrun = -INFINITY, lrun = 0.f;

    // staging: K tile 4KB (thread: key=t/4, d0=(t&3)*8), Vt tile 4KB
    // (thread: d=t/8, k0=(t&7)*8); LDS dest linear at t*16 bytes.
    const int kkey = tid >> 2, kd0 = (tid & 3) * 8;
    const int vd   = tid >> 3, vk0 = (tid & 7) * 8;

    // prologue
    gl_lds16(kp + (size_t)kkey * HDIM + kd0, (void*)(&Kl[0][0] + tid * 8));
    gl_lds16(vtp + (size_t)vd * S_LEN + vk0, (void*)(&Vl[0][0] + tid * 8));
    __syncthreads();

    int cur = 0;
    for (int kt = 0; kt < 16; ++kt) {
        if (kt + 1 < 16) {
            const int kb2 = (kt + 1) * 64;
            gl_lds16(kp + (size_t)(kb2 + kkey) * HDIM + kd0,
                     (void*)(&Kl[cur ^ 1][0] + tid * 8));
            gl_lds16(vtp + (size_t)vd * S_LEN + kb2 + vk0,
                     (void*)(&Vl[cur ^ 1][0] + tid * 8));
        }
        __hip_bfloat16* Pw = &Pl[w][0];

        // ---- QK^T: 4 MFMAs, scores^T tile; lane: q=q15, keys sub*16+4g+r
        f32x4 sc[4];
        #pragma unroll
        for (int sub = 0; sub < 4; ++sub) {
            bf16x8 kf = *(const bf16x8*)(&Kl[cur][(sub * 16 + q15) * HDIM + 8 * g]);
            f32x4 z = {0.f, 0.f, 0.f, 0.f};
            sc[sub] = __builtin_amdgcn_mfma_f32_16x16x32_bf16(kf, qf, z, 0, 0, 0);
        }

        // ---- online softmax (log2 domain; q pre-scaled by scale*log2e)
        float tm = sc[0][0];
        #pragma unroll
        for (int sub = 0; sub < 4; ++sub)
            #pragma unroll
            for (int r = 0; r < 4; ++r) tm = fmaxf(tm, sc[sub][r]);
        tm = fmaxf(tm, __shfl_xor(tm, 16));
        tm = fmaxf(tm, __shfl_xor(tm, 32));
        const float mnew  = fmaxf(mrun, tm);
        const float alpha = __builtin_amdgcn_exp2f(mrun - mnew);
        float psum = 0.f;
        #pragma unroll
        for (int sub = 0; sub < 4; ++sub) {
            bf16x4 pk;
            #pragma unroll
            for (int r = 0; r < 4; ++r) {
                float p = __builtin_amdgcn_exp2f(sc[sub][r] - mnew);
                psum += p;
                pk[r] = (short)f2bf(p);
            }
            *(bf16x4*)(Pw + q15 * 72 + sub * 16 + 4 * g) = pk;
        }
        psum += __shfl_xor(psum, 16);
        psum += __shfl_xor(psum, 32);
        lrun = lrun * alpha + psum;
        mrun = mnew;

        // ---- rescale O (acc lane holds queries 4g+r)
        const float a0 = __shfl(alpha, 4 * g + 0);
        const float a1 = __shfl(alpha, 4 * g + 1);
        const float a2 = __shfl(alpha, 4 * g + 2);
        const float a3 = __shfl(alpha, 4 * g + 3);
        acc0[0] *= a0; acc0[1] *= a1; acc0[2] *= a2; acc0[3] *= a3;
        acc1[0] *= a0; acc1[1] *= a1; acc1[2] *= a2; acc1[3] *= a3;

        // ---- PV: P (A) x Vt (B), 2 kchunks x 2 dtiles
        #pragma unroll
        for (int kc = 0; kc < 2; ++kc) {
            bf16x8 pf = *(const bf16x8*)(Pw + q15 * 72 + kc * 32 + 8 * g);
            bf16x8 v0 = *(const bf16x8*)(&Vl[cur][q15 * 64 + kc * 32 + 8 * g]);
            bf16x8 v1 = *(const bf16x8*)(&Vl[cur][(16 + q15) * 64 + kc * 32 + 8 * g]);
            acc0 = __builtin_amdgcn_mfma_f32_16x16x32_bf16(pf, v0, acc0, 0, 0, 0);
            acc1 = __builtin_amdgcn_mfma_f32_16x16x32_bf16(pf, v1, acc1, 0, 0, 0);
        }

        __syncthreads();   // drains vmcnt: next tile staged; compute done
        cur ^= 1;
    }

    // ---- epilogue: normalize, write (S,B,E) fp32
    const float inv = 1.f / lrun;
    float iv[4];
    iv[0] = __shfl(inv, 4 * g + 0);
    iv[1] = __shfl(inv, 4 * g + 1);
    iv[2] = __shfl(inv, 4 * g + 2);
    iv[3] = __shfl(inv, 4 * g + 3);
    const int b = bh >> 2, h = bh & 3;
    #pragma unroll
    for (int r = 0; r < 4; ++r) {
        const int srow = qt * 64 + w * 16 + 4 * g + r;
        size_t base = ((size_t)srow * BATCH + b) * EMB + h * HDIM;
        attn[base + q15]      = acc0[r] * iv[r];
        attn[base + 16 + q15] = acc1[r] * iv[r];
    }
}

// ---------------- Kernel 3: out_proj + bias + residual + LayerNorm ----------
__global__ __launch_bounds__(256)
void proj_ln_kernel(const float* __restrict__ x, const float* __restrict__ wo,
                    const float* __restrict__ bo, const float* __restrict__ gm,
                    const float* __restrict__ bt, float* out)
{
    __shared__ float as[8][132];
    __shared__ float wsh[64][132];
    const int tid  = threadIdx.x;
    const int tile = blockIdx.x;

    {
        const float4* ag = (const float4*)(out + (size_t)tile * (8 * EMB));
        int idx = tid;
        float4 v = ag[idx];
        int tok = idx >> 5, k4 = idx & 31;
        *(float4*)&as[tok][k4 * 4] = v;
    }

    const float4* wg = (const float4*)wo;
    const int tok  = tid >> 5;
    const int fgrp = tid & 31;
    float acc[4];

    for (int half = 0; half < 2; ++half) {
        if (half) __syncthreads();
        #pragma unroll
        for (int j = 0; j < 8; ++j) {
            int idx = tid + j * 256;
            float4 v = wg[half * 2048 + idx];
            int f = idx >> 5, k4 = idx & 31;
            *(float4*)&wsh[f][k4 * 4] = v;
        }
        __syncthreads();
        acc[half * 2 + 0] = 0.f;
        acc[half * 2 + 1] = 0.f;
        #pragma unroll
        for (int k4 = 0; k4 < 32; ++k4) {
            float4 a = *(const float4*)&as[tok][k4 * 4];
            #pragma unroll
            for (int c = 0; c < 2; ++c) {
                float4 b = *(const float4*)&wsh[fgrp + 32 * c][k4 * 4];
                int i = half * 2 + c;
                acc[i] = fmaf(a.x, b.x, acc[i]);
                acc[i] = fmaf(a.y, b.y, acc[i]);
                acc[i] = fmaf(a.z, b.z, acc[i]);
                acc[i] = fmaf(a.w, b.w, acc[i]);
            }
        }
    }
    const int t = tile * 8 + tok;
    float vals[4];
    float sum = 0.f, sq = 0.f;
    #pragma unroll
    for (int i = 0; i < 4; ++i) {
        int f = fgrp + 32 * i;
        float v = acc[i] + bo[f] + x[(size_t)t * EMB + f];
        vals[i] = v;
        sum += v;
        sq = fmaf(v, v, sq);
    }
    #pragma unroll
    for (int sft = 1; sft < 32; sft <<= 1) {
        sum += __shfl_xor(sum, sft);
        sq  += __shfl_xor(sq, sft);
    }
    const float mean = sum * (1.f / 128.f);
    const float var  = sq * (1.f / 128.f) - mean * mean;
    const float rstd = rsqrtf(var + 1e-5f);
    #pragma unroll
    for (int i = 0; i < 4; ++i) {
        int f = fgrp + 32 * i;
        out[(size_t)t * EMB + f] = (vals[i] - mean) * rstd * gm[f] + bt[f];
    }
}

extern "C" void kernel_launch(void* const* d_in, const int* in_sizes, int n_in,
                              void* d_out, int out_size, void* d_ws, size_t ws_size,
                              hipStream_t stream) {
    const float* x     = (const float*)d_in[0];
    const float* wi    = (const float*)d_in[1];
    const float* bi    = (const float*)d_in[2];
    const float* wo    = (const float*)d_in[3];
    const float* bo    = (const float*)d_in[4];
    const float* gamma = (const float*)d_in[5];
    const float* beta  = (const float*)d_in[6];
    float* out = (float*)d_out;
    __hip_bfloat16* qb  = (__hip_bfloat16*)d_ws;      // 3*HBUF bf16 = 24 MB
    __hip_bfloat16* kb  = qb + HBUF;
    __hip_bfloat16* vtb = kb + HBUF;

    qkv_kernel<<<dim3(2048, 6), 256, 0, stream>>>(x, wi, bi, qb, kb, vtb);
    attn_kernel<<<dim3(BHN, 16), 256, 0, stream>>>(qb, kb, vtb, out);
    proj_ln_kernel<<<4096, 256, 0, stream>>>(x, wo, bo, gamma, beta, out);
}

// Round 4
// 158.226 us; speedup vs baseline: 3.3312x; 1.9045x over previous
//
#include <hip/hip_runtime.h>
#include <hip/hip_bf16.h>
#include <math.h>

#define S_LEN 1024
#define BATCH 32
#define EMB   128
#define NHEAD 4
#define HDIM  32
#define BHN   (BATCH*NHEAD)          // 128
#define HBUF  (BHN*S_LEN*HDIM)       // 4194304 elements per q/k/v (bf16)

typedef __attribute__((ext_vector_type(4))) float f32x4;
typedef __attribute__((ext_vector_type(8))) short bf16x8;
typedef __attribute__((ext_vector_type(4))) short bf16x4;

// (1/sqrt(32)) * log2(e): folded into Wq/bq by wcvt_kernel
#define Q_PRESCALE 0.25503588f

__device__ __forceinline__ unsigned short f2bf(float f) {
    union { float f; unsigned u; } v; v.f = f;
    unsigned r = v.u + 0x7fff + ((v.u >> 16) & 1);   // RNE
    return (unsigned short)(r >> 16);
}

__device__ __forceinline__ void gl_lds16(const void* g, void* l) {
    __builtin_amdgcn_global_load_lds(
        (const __attribute__((address_space(1))) unsigned*)g,
        (__attribute__((address_space(3))) unsigned*)l, 16, 0, 0);
}

// ---------------- Kernel 0: W/bias convert (fp32 -> bf16, q-prescale) ------
// grid 49 x 256. Blocks 0..47: W (49152 elems). Block 48: bias (384, fp32 copy).
__global__ __launch_bounds__(256)
void wcvt_kernel(const float* __restrict__ w, const float* __restrict__ bias,
                 __hip_bfloat16* __restrict__ wbf, float* __restrict__ biasf)
{
    const int bid = blockIdx.x, tid = threadIdx.x;
    if (bid < 48) {
        int e = bid * 1024 + tid * 4;
        float4 v = *(const float4*)(w + e);
        float s = (e < 128 * 128) ? Q_PRESCALE : 1.f;
        bf16x4 o;
        o[0] = (short)f2bf(v.x * s); o[1] = (short)f2bf(v.y * s);
        o[2] = (short)f2bf(v.z * s); o[3] = (short)f2bf(v.w * s);
        *(bf16x4*)(wbf + e) = o;
    } else if (tid < 96) {
        int e = tid * 4;
        float4 v = *(const float4*)(bias + e);
        float s = (e < 128) ? Q_PRESCALE : 1.f;
        v.x *= s; v.y *= s; v.z *= s; v.w *= s;
        *(float4*)(biasf + e) = v;
    }
}

// ---------------- Kernel 1: QKV projection, bf16 MFMA ----------------
// grid (512, 3): x = token tile (4 b x 16 s), y = which of q/k/v (128 f each).
// block 256 = 4 waves in 2x2 (wm: token half, wn: f half). 32 MFMA/wave.
__global__ __launch_bounds__(256)
void qkv_mfma_kernel(const float* __restrict__ x,
                     const __hip_bfloat16* __restrict__ wbf,
                     const float* __restrict__ biasf,
                     __hip_bfloat16* __restrict__ qb,
                     __hip_bfloat16* __restrict__ kb,
                     __hip_bfloat16* __restrict__ vtb)
{
    __shared__ __align__(16) unsigned char smem[17408 + 32768];
    __hip_bfloat16* xs = (__hip_bfloat16*)smem;            // [64][136] padded
    __hip_bfloat16* wl = (__hip_bfloat16*)(smem + 17408);  // [128][128] XOR-swz
    const int tid   = threadIdx.x;
    const int mt    = blockIdx.x;
    const int which = blockIdx.y;        // 0=q 1=k 2=v
    const int b0 = (mt & 7) * 4;
    const int s0 = (mt >> 3) * 16;

    // ---- stage W section via global_load_lds, source-XOR-swizzled
    const __hip_bfloat16* wsec = wbf + which * (128 * 128);
    #pragma unroll
    for (int j = 0; j < 8; ++j) {
        int idx = tid + j * 256;             // 0..2047
        int fl = idx >> 4, c = idx & 15;
        int cs = c ^ (fl & 15);
        gl_lds16(wsec + fl * 128 + cs * 8, wl + idx * 8);
    }
    // ---- stage x tile: fp32 -> bf16, padded pitch 136
    #pragma unroll
    for (int j = 0; j < 8; ++j) {
        int idx = tid + j * 256;             // 0..2047
        int lt = idx >> 5, c4 = idx & 31;
        int t = (s0 + (lt & 15)) * 32 + b0 + (lt >> 4);
        float4 v = *(const float4*)(x + (size_t)t * 128 + c4 * 4);
        bf16x4 o;
        o[0] = (short)f2bf(v.x); o[1] = (short)f2bf(v.y);
        o[2] = (short)f2bf(v.z); o[3] = (short)f2bf(v.w);
        *(bf16x4*)(xs + lt * 136 + c4 * 4) = o;
    }
    __syncthreads();

    const int wv = tid >> 6, wm = wv >> 1, wn = wv & 1;
    const int l = tid & 63, q15 = l & 15, g = l >> 4;

    // x fragments (B operand): token row = wm*32 + tt*16 + q15
    bf16x8 xf[2][4];
    #pragma unroll
    for (int tt = 0; tt < 2; ++tt)
        #pragma unroll
        for (int kc = 0; kc < 4; ++kc)
            xf[tt][kc] = *(const bf16x8*)(xs + (wm * 32 + tt * 16 + q15) * 136
                                          + kc * 32 + 8 * g);

    f32x4 acc[4][2];
    #pragma unroll
    for (int nt = 0; nt < 4; ++nt)
        #pragma unroll
        for (int tt = 0; tt < 2; ++tt)
            acc[nt][tt] = (f32x4){0.f, 0.f, 0.f, 0.f};

    #pragma unroll
    for (int nt = 0; nt < 4; ++nt) {
        const int fl = wn * 64 + nt * 16 + q15;
        #pragma unroll
        for (int kc = 0; kc < 4; ++kc) {
            bf16x8 wf = *(const bf16x8*)(wl + fl * 128
                                         + (((kc * 4 + g) ^ q15) * 8));
            acc[nt][0] = __builtin_amdgcn_mfma_f32_16x16x32_bf16(wf, xf[0][kc], acc[nt][0], 0, 0, 0);
            acc[nt][1] = __builtin_amdgcn_mfma_f32_16x16x32_bf16(wf, xf[1][kc], acc[nt][1], 0, 0, 0);
        }
    }
    __syncthreads();     // all wl/xs reads done; reuse wl as out-transpose buf
    __hip_bfloat16* ol = wl;

    if (which < 2) {
        // out layout [64 tokens][f, pitch 136]
        #pragma unroll
        for (int nt = 0; nt < 4; ++nt) {
            float4 bv = *(const float4*)(biasf + which * 128 + wn * 64 + nt * 16 + 4 * g);
            #pragma unroll
            for (int tt = 0; tt < 2; ++tt) {
                bf16x4 pk;
                pk[0] = (short)f2bf(acc[nt][tt][0] + bv.x);
                pk[1] = (short)f2bf(acc[nt][tt][1] + bv.y);
                pk[2] = (short)f2bf(acc[nt][tt][2] + bv.z);
                pk[3] = (short)f2bf(acc[nt][tt][3] + bv.w);
                *(bf16x4*)(ol + (wm * 32 + tt * 16 + q15) * 136
                           + wn * 64 + nt * 16 + 4 * g) = pk;
            }
        }
        __syncthreads();
        // coalesced store to (B,H,S,D): lanes cover 16 s x 4 d-chunks = 1KB
        const int bb = tid >> 6, rr = tid & 63, ss = rr >> 2, c4 = rr & 3;
        __hip_bfloat16* dst = (which == 0) ? qb : kb;
        #pragma unroll
        for (int i = 0; i < 4; ++i) {    // i = h
            bf16x8 vv = *(const bf16x8*)(ol + (bb * 16 + ss) * 136 + i * 32 + c4 * 8);
            *(bf16x8*)(dst + ((size_t)((b0 + bb) * 4 + i)) * 32768
                       + (s0 + ss) * 32 + c4 * 8) = vv;
        }
    } else {
        // v: out layout [128 f][token, pitch 72] (transposed)
        #pragma unroll
        for (int nt = 0; nt < 4; ++nt) {
            float4 bv = *(const float4*)(biasf + 256 + wn * 64 + nt * 16 + 4 * g);
            const float* bvp = (const float*)&bv;
            #pragma unroll
            for (int tt = 0; tt < 2; ++tt) {
                #pragma unroll
                for (int r = 0; r < 4; ++r) {
                    int f = wn * 64 + nt * 16 + 4 * g + r;
                    ol[f * 72 + wm * 32 + tt * 16 + q15] =
                        __float2bfloat16(acc[nt][tt][r] + bvp[r]);
                }
            }
        }
        __syncthreads();
        // coalesced store to (B,H,D,S)
        const int bb = tid >> 6, rr = tid & 63, fln = rr >> 1, sh = rr & 1;
        #pragma unroll
        for (int i = 0; i < 4; ++i) {    // i = h
            int f = i * 32 + fln;        // d = fln, h = i
            bf16x8 vv = *(const bf16x8*)(ol + f * 72 + bb * 16 + sh * 8);
            *(bf16x8*)(vtb + ((size_t)((b0 + bb) * 4 + i)) * 32768
                       + (size_t)fln * 1024 + s0 + sh * 8) = vv;
        }
    }
}

// ---------------- Kernel 2: flash attention, bf16 MFMA ----------------
// grid (BH=128, S/64=16), block 256 (4 waves, 16 queries/wave).
__global__ __launch_bounds__(256)
void attn_kernel(const __hip_bfloat16* __restrict__ qg,
                 const __hip_bfloat16* __restrict__ kg,
                 const __hip_bfloat16* __restrict__ vtg,
                 float* __restrict__ attn)
{
    __shared__ __hip_bfloat16 Kl[2][64 * 32];   // [key][d] linear
    __shared__ __hip_bfloat16 Vl[2][32 * 64];   // [d][key] linear (Vt)
    __shared__ __hip_bfloat16 Pl[4][16 * 72];   // per-wave P, pitch 72 bf16

    const int tid = threadIdx.x;
    const int w   = tid >> 6;
    const int l   = tid & 63;
    const int q15 = l & 15;
    const int g   = l >> 4;
    const int bh  = blockIdx.x;
    const int qt  = blockIdx.y;

    const __hip_bfloat16* kp  = kg  + (size_t)bh * (S_LEN * HDIM);
    const __hip_bfloat16* vtp = vtg + (size_t)bh * (HDIM * S_LEN);

    bf16x8 qf = *(const bf16x8*)(qg + (size_t)bh * (S_LEN * HDIM)
                                 + (size_t)(qt * 64 + w * 16 + q15) * HDIM + 8 * g);

    f32x4 acc0 = {0.f, 0.f, 0.f, 0.f};
    f32x4 acc1 = {0.f, 0.f, 0.f, 0.f};
    float mrun = -INFINITY, lrun = 0.f;

    const int kkey = tid >> 2, kd0 = (tid & 3) * 8;
    const int vd   = tid >> 3, vk0 = (tid & 7) * 8;

    gl_lds16(kp + (size_t)kkey * HDIM + kd0, (void*)(&Kl[0][0] + tid * 8));
    gl_lds16(vtp + (size_t)vd * S_LEN + vk0, (void*)(&Vl[0][0] + tid * 8));
    __syncthreads();

    int cur = 0;
    for (int kt = 0; kt < 16; ++kt) {
        if (kt + 1 < 16) {
            const int kb2 = (kt + 1) * 64;
            gl_lds16(kp + (size_t)(kb2 + kkey) * HDIM + kd0,
                     (void*)(&Kl[cur ^ 1][0] + tid * 8));
            gl_lds16(vtp + (size_t)vd * S_LEN + kb2 + vk0,
                     (void*)(&Vl[cur ^ 1][0] + tid * 8));
        }
        __hip_bfloat16* Pw = &Pl[w][0];

        f32x4 sc[4];
        #pragma unroll
        for (int sub = 0; sub < 4; ++sub) {
            bf16x8 kf = *(const bf16x8*)(&Kl[cur][(sub * 16 + q15) * HDIM + 8 * g]);
            f32x4 z = {0.f, 0.f, 0.f, 0.f};
            sc[sub] = __builtin_amdgcn_mfma_f32_16x16x32_bf16(kf, qf, z, 0, 0, 0);
        }

        float tm = sc[0][0];
        #pragma unroll
        for (int sub = 0; sub < 4; ++sub)
            #pragma unroll
            for (int r = 0; r < 4; ++r) tm = fmaxf(tm, sc[sub][r]);
        tm = fmaxf(tm, __shfl_xor(tm, 16));
        tm = fmaxf(tm, __shfl_xor(tm, 32));
        const float mnew  = fmaxf(mrun, tm);
        const float alpha = __builtin_amdgcn_exp2f(mrun - mnew);
        float psum = 0.f;
        #pragma unroll
        for (int sub = 0; sub < 4; ++sub) {
            bf16x4 pk;
            #pragma unroll
            for (int r = 0; r < 4; ++r) {
                float p = __builtin_amdgcn_exp2f(sc[sub][r] - mnew);
                psum += p;
                pk[r] = (short)f2bf(p);
            }
            *(bf16x4*)(Pw + q15 * 72 + sub * 16 + 4 * g) = pk;
        }
        psum += __shfl_xor(psum, 16);
        psum += __shfl_xor(psum, 32);
        lrun = lrun * alpha + psum;
        mrun = mnew;

        const float a0 = __shfl(alpha, 4 * g + 0);
        const float a1 = __shfl(alpha, 4 * g + 1);
        const float a2 = __shfl(alpha, 4 * g + 2);
        const float a3 = __shfl(alpha, 4 * g + 3);
        acc0[0] *= a0; acc0[1] *= a1; acc0[2] *= a2; acc0[3] *= a3;
        acc1[0] *= a0; acc1[1] *= a1; acc1[2] *= a2; acc1[3] *= a3;

        #pragma unroll
        for (int kc = 0; kc < 2; ++kc) {
            bf16x8 pf = *(const bf16x8*)(Pw + q15 * 72 + kc * 32 + 8 * g);
            bf16x8 v0 = *(const bf16x8*)(&Vl[cur][q15 * 64 + kc * 32 + 8 * g]);
            bf16x8 v1 = *(const bf16x8*)(&Vl[cur][(16 + q15) * 64 + kc * 32 + 8 * g]);
            acc0 = __builtin_amdgcn_mfma_f32_16x16x32_bf16(pf, v0, acc0, 0, 0, 0);
            acc1 = __builtin_amdgcn_mfma_f32_16x16x32_bf16(pf, v1, acc1, 0, 0, 0);
        }

        __syncthreads();
        cur ^= 1;
    }

    const float inv = 1.f / lrun;
    float iv[4];
    iv[0] = __shfl(inv, 4 * g + 0);
    iv[1] = __shfl(inv, 4 * g + 1);
    iv[2] = __shfl(inv, 4 * g + 2);
    iv[3] = __shfl(inv, 4 * g + 3);
    const int b = bh >> 2, h = bh & 3;
    #pragma unroll
    for (int r = 0; r < 4; ++r) {
        const int srow = qt * 64 + w * 16 + 4 * g + r;
        size_t base = ((size_t)srow * BATCH + b) * EMB + h * HDIM;
        attn[base + q15]      = acc0[r] * iv[r];
        attn[base + 16 + q15] = acc1[r] * iv[r];
    }
}

// ---------------- Kernel 3: out_proj + bias + residual + LayerNorm ----------
__global__ __launch_bounds__(256)
void proj_ln_kernel(const float* __restrict__ x, const float* __restrict__ wo,
                    const float* __restrict__ bo, const float* __restrict__ gm,
                    const float* __restrict__ bt, float* out)
{
    __shared__ float as[8][132];
    __shared__ float wsh[64][132];
    const int tid  = threadIdx.x;
    const int tile = blockIdx.x;

    {
        const float4* ag = (const float4*)(out + (size_t)tile * (8 * EMB));
        int idx = tid;
        float4 v = ag[idx];
        int tok = idx >> 5, k4 = idx & 31;
        *(float4*)&as[tok][k4 * 4] = v;
    }

    const float4* wg = (const float4*)wo;
    const int tok  = tid >> 5;
    const int fgrp = tid & 31;
    float acc[4];

    for (int half = 0; half < 2; ++half) {
        if (half) __syncthreads();
        #pragma unroll
        for (int j = 0; j < 8; ++j) {
            int idx = tid + j * 256;
            float4 v = wg[half * 2048 + idx];
            int f = idx >> 5, k4 = idx & 31;
            *(float4*)&wsh[f][k4 * 4] = v;
        }
        __syncthreads();
        acc[half * 2 + 0] = 0.f;
        acc[half * 2 + 1] = 0.f;
        #pragma unroll
        for (int k4 = 0; k4 < 32; ++k4) {
            float4 a = *(const float4*)&as[tok][k4 * 4];
            #pragma unroll
            for (int c = 0; c < 2; ++c) {
                float4 b = *(const float4*)&wsh[fgrp + 32 * c][k4 * 4];
                int i = half * 2 + c;
                acc[i] = fmaf(a.x, b.x, acc[i]);
                acc[i] = fmaf(a.y, b.y, acc[i]);
                acc[i] = fmaf(a.z, b.z, acc[i]);
                acc[i] = fmaf(a.w, b.w, acc[i]);
            }
        }
    }
    const int t = tile * 8 + tok;
    float vals[4];
    float sum = 0.f, sq = 0.f;
    #pragma unroll
    for (int i = 0; i < 4; ++i) {
        int f = fgrp + 32 * i;
        float v = acc[i] + bo[f] + x[(size_t)t * EMB + f];
        vals[i] = v;
        sum += v;
        sq = fmaf(v, v, sq);
    }
    #pragma unroll
    for (int sft = 1; sft < 32; sft <<= 1) {
        sum += __shfl_xor(sum, sft);
        sq  += __shfl_xor(sq, sft);
    }
    const float mean = sum * (1.f / 128.f);
    const float var  = sq * (1.f / 128.f) - mean * mean;
    const float rstd = rsqrtf(var + 1e-5f);
    #pragma unroll
    for (int i = 0; i < 4; ++i) {
        int f = fgrp + 32 * i;
        out[(size_t)t * EMB + f] = (vals[i] - mean) * rstd * gm[f] + bt[f];
    }
}

extern "C" void kernel_launch(void* const* d_in, const int* in_sizes, int n_in,
                              void* d_out, int out_size, void* d_ws, size_t ws_size,
                              hipStream_t stream) {
    const float* x     = (const float*)d_in[0];
    const float* wi    = (const float*)d_in[1];
    const float* bi    = (const float*)d_in[2];
    const float* wo    = (const float*)d_in[3];
    const float* bo    = (const float*)d_in[4];
    const float* gamma = (const float*)d_in[5];
    const float* beta  = (const float*)d_in[6];
    float* out = (float*)d_out;

    unsigned char* wsb = (unsigned char*)d_ws;
    __hip_bfloat16* wbf   = (__hip_bfloat16*)wsb;             // 98304 B
    float*          biasf = (float*)(wsb + 98304);            // 1536 B
    __hip_bfloat16* qb    = (__hip_bfloat16*)(wsb + 99840);   // 8 MB each
    __hip_bfloat16* kb    = qb + HBUF;
    __hip_bfloat16* vtb   = kb + HBUF;

    wcvt_kernel<<<49, 256, 0, stream>>>(wi, bi, wbf, biasf);
    qkv_mfma_kernel<<<dim3(512, 3), 256, 0, stream>>>(x, wbf, biasf, qb, kb, vtb);
    attn_kernel<<<dim3(BHN, 16), 256, 0, stream>>>(qb, kb, vtb, out);
    proj_ln_kernel<<<4096, 256, 0, stream>>>(x, wo, bo, gamma, beta, out);
}

// Round 5
// 87.866 us; speedup vs baseline: 5.9987x; 1.8008x over previous
//
#include <hip/hip_runtime.h>
#include <hip/hip_bf16.h>
#include <math.h>

#define S_LEN 1024
#define BATCH 32
#define EMB   128
#define NHEAD 4
#define HDIM  32
#define BHN   (BATCH*NHEAD)          // 128
#define HBUF  (BHN*S_LEN*HDIM)       // 4194304 elements per q/k/v (bf16)
#define NTOK  (S_LEN*BATCH)          // 32768

typedef __attribute__((ext_vector_type(4))) float f32x4;
typedef __attribute__((ext_vector_type(8))) short bf16x8;
typedef __attribute__((ext_vector_type(4))) short bf16x4;

// (1/sqrt(32)) * log2(e): folded into Wq/bq by wcvt_kernel
#define Q_PRESCALE 0.25503588f

__device__ __forceinline__ unsigned short f2bf(float f) {
    union { float f; unsigned u; } v; v.f = f;
    unsigned r = v.u + 0x7fff + ((v.u >> 16) & 1);   // RNE
    return (unsigned short)(r >> 16);
}

__device__ __forceinline__ void gl_lds16(const void* g, void* l) {
    __builtin_amdgcn_global_load_lds(
        (const __attribute__((address_space(1))) unsigned*)g,
        (__attribute__((address_space(3))) unsigned*)l, 16, 0, 0);
}

// ---------------- Kernel 0: weight/bias convert (fp32 -> bf16) -------------
// Blocks 0..47: in_proj_w. Blocks 48..63: out_proj_w. Block 64: biases.
__global__ __launch_bounds__(256)
void wcvt_kernel(const float* __restrict__ w, const float* __restrict__ bias,
                 const float* __restrict__ wo, const float* __restrict__ bo,
                 __hip_bfloat16* __restrict__ wbf,
                 __hip_bfloat16* __restrict__ wobf,
                 float* __restrict__ biasf)
{
    const int bid = blockIdx.x, tid = threadIdx.x;
    if (bid < 48) {
        int e = bid * 1024 + tid * 4;
        float4 v = *(const float4*)(w + e);
        float s = (e < 128 * 128) ? Q_PRESCALE : 1.f;
        bf16x4 o;
        o[0] = (short)f2bf(v.x * s); o[1] = (short)f2bf(v.y * s);
        o[2] = (short)f2bf(v.z * s); o[3] = (short)f2bf(v.w * s);
        *(bf16x4*)(wbf + e) = o;
    } else if (bid < 64) {
        int e = (bid - 48) * 1024 + tid * 4;
        float4 v = *(const float4*)(wo + e);
        bf16x4 o;
        o[0] = (short)f2bf(v.x); o[1] = (short)f2bf(v.y);
        o[2] = (short)f2bf(v.z); o[3] = (short)f2bf(v.w);
        *(bf16x4*)(wobf + e) = o;
    } else if (tid < 96) {
        int e = tid * 4;
        float4 v = *(const float4*)(bias + e);
        float s = (e < 128) ? Q_PRESCALE : 1.f;
        v.x *= s; v.y *= s; v.z *= s; v.w *= s;
        *(float4*)(biasf + e) = v;
    } else if (tid < 128) {
        int e = (tid - 96) * 4;
        *(float4*)(biasf + 384 + e) = *(const float4*)(bo + e);
    }
}

// ---------------- Kernel 1: QKV projection, bf16 MFMA ----------------
__global__ __launch_bounds__(256)
void qkv_mfma_kernel(const float* __restrict__ x,
                     const __hip_bfloat16* __restrict__ wbf,
                     const float* __restrict__ biasf,
                     __hip_bfloat16* __restrict__ qb,
                     __hip_bfloat16* __restrict__ kb,
                     __hip_bfloat16* __restrict__ vtb)
{
    __shared__ __align__(16) unsigned char smem[17408 + 32768];
    __hip_bfloat16* xs = (__hip_bfloat16*)smem;            // [64][136] padded
    __hip_bfloat16* wl = (__hip_bfloat16*)(smem + 17408);  // [128][128] XOR-swz
    const int tid   = threadIdx.x;
    const int mt    = blockIdx.x;
    const int which = blockIdx.y;        // 0=q 1=k 2=v
    const int b0 = (mt & 7) * 4;
    const int s0 = (mt >> 3) * 16;

    const __hip_bfloat16* wsec = wbf + which * (128 * 128);
    #pragma unroll
    for (int j = 0; j < 8; ++j) {
        int idx = tid + j * 256;
        int fl = idx >> 4, c = idx & 15;
        int cs = c ^ (fl & 15);
        gl_lds16(wsec + fl * 128 + cs * 8, wl + idx * 8);
    }
    #pragma unroll
    for (int j = 0; j < 8; ++j) {
        int idx = tid + j * 256;
        int lt = idx >> 5, c4 = idx & 31;
        int t = (s0 + (lt & 15)) * 32 + b0 + (lt >> 4);
        float4 v = *(const float4*)(x + (size_t)t * 128 + c4 * 4);
        bf16x4 o;
        o[0] = (short)f2bf(v.x); o[1] = (short)f2bf(v.y);
        o[2] = (short)f2bf(v.z); o[3] = (short)f2bf(v.w);
        *(bf16x4*)(xs + lt * 136 + c4 * 4) = o;
    }
    __syncthreads();

    const int wv = tid >> 6, wm = wv >> 1, wn = wv & 1;
    const int l = tid & 63, q15 = l & 15, g = l >> 4;

    bf16x8 xf[2][4];
    #pragma unroll
    for (int tt = 0; tt < 2; ++tt)
        #pragma unroll
        for (int kc = 0; kc < 4; ++kc)
            xf[tt][kc] = *(const bf16x8*)(xs + (wm * 32 + tt * 16 + q15) * 136
                                          + kc * 32 + 8 * g);

    f32x4 acc[4][2];
    #pragma unroll
    for (int nt = 0; nt < 4; ++nt)
        #pragma unroll
        for (int tt = 0; tt < 2; ++tt)
            acc[nt][tt] = (f32x4){0.f, 0.f, 0.f, 0.f};

    #pragma unroll
    for (int nt = 0; nt < 4; ++nt) {
        const int fl = wn * 64 + nt * 16 + q15;
        #pragma unroll
        for (int kc = 0; kc < 4; ++kc) {
            bf16x8 wf = *(const bf16x8*)(wl + fl * 128
                                         + (((kc * 4 + g) ^ q15) * 8));
            acc[nt][0] = __builtin_amdgcn_mfma_f32_16x16x32_bf16(wf, xf[0][kc], acc[nt][0], 0, 0, 0);
            acc[nt][1] = __builtin_amdgcn_mfma_f32_16x16x32_bf16(wf, xf[1][kc], acc[nt][1], 0, 0, 0);
        }
    }
    __syncthreads();
    __hip_bfloat16* ol = wl;

    if (which < 2) {
        #pragma unroll
        for (int nt = 0; nt < 4; ++nt) {
            float4 bv = *(const float4*)(biasf + which * 128 + wn * 64 + nt * 16 + 4 * g);
            #pragma unroll
            for (int tt = 0; tt < 2; ++tt) {
                bf16x4 pk;
                pk[0] = (short)f2bf(acc[nt][tt][0] + bv.x);
                pk[1] = (short)f2bf(acc[nt][tt][1] + bv.y);
                pk[2] = (short)f2bf(acc[nt][tt][2] + bv.z);
                pk[3] = (short)f2bf(acc[nt][tt][3] + bv.w);
                *(bf16x4*)(ol + (wm * 32 + tt * 16 + q15) * 136
                           + wn * 64 + nt * 16 + 4 * g) = pk;
            }
        }
        __syncthreads();
        const int bb = tid >> 6, rr = tid & 63, ss = rr >> 2, c4 = rr & 3;
        __hip_bfloat16* dst = (which == 0) ? qb : kb;
        #pragma unroll
        for (int i = 0; i < 4; ++i) {
            bf16x8 vv = *(const bf16x8*)(ol + (bb * 16 + ss) * 136 + i * 32 + c4 * 8);
            *(bf16x8*)(dst + ((size_t)((b0 + bb) * 4 + i)) * 32768
                       + (s0 + ss) * 32 + c4 * 8) = vv;
        }
    } else {
        #pragma unroll
        for (int nt = 0; nt < 4; ++nt) {
            float4 bv = *(const float4*)(biasf + 256 + wn * 64 + nt * 16 + 4 * g);
            const float* bvp = (const float*)&bv;
            #pragma unroll
            for (int tt = 0; tt < 2; ++tt) {
                #pragma unroll
                for (int r = 0; r < 4; ++r) {
                    int f = wn * 64 + nt * 16 + 4 * g + r;
                    ol[f * 72 + wm * 32 + tt * 16 + q15] =
                        __float2bfloat16(acc[nt][tt][r] + bvp[r]);
                }
            }
        }
        __syncthreads();
        const int bb = tid >> 6, rr = tid & 63, fln = rr >> 1, sh = rr & 1;
        #pragma unroll
        for (int i = 0; i < 4; ++i) {
            int f = i * 32 + fln;
            bf16x8 vv = *(const bf16x8*)(ol + f * 72 + bb * 16 + sh * 8);
            *(bf16x8*)(vtb + ((size_t)((b0 + bb) * 4 + i)) * 32768
                       + (size_t)fln * 1024 + s0 + sh * 8) = vv;
        }
    }
}

// ---------------- Kernel 2: flash attention, bf16 MFMA ----------------
// Output now bf16 in (S*B, E) into workspace.
__global__ __launch_bounds__(256)
void attn_kernel(const __hip_bfloat16* __restrict__ qg,
                 const __hip_bfloat16* __restrict__ kg,
                 const __hip_bfloat16* __restrict__ vtg,
                 __hip_bfloat16* __restrict__ att)
{
    __shared__ __hip_bfloat16 Kl[2][64 * 32];
    __shared__ __hip_bfloat16 Vl[2][32 * 64];
    __shared__ __hip_bfloat16 Pl[4][16 * 72];

    const int tid = threadIdx.x;
    const int w   = tid >> 6;
    const int l   = tid & 63;
    const int q15 = l & 15;
    const int g   = l >> 4;
    const int bh  = blockIdx.x;
    const int qt  = blockIdx.y;

    const __hip_bfloat16* kp  = kg  + (size_t)bh * (S_LEN * HDIM);
    const __hip_bfloat16* vtp = vtg + (size_t)bh * (HDIM * S_LEN);

    bf16x8 qf = *(const bf16x8*)(qg + (size_t)bh * (S_LEN * HDIM)
                                 + (size_t)(qt * 64 + w * 16 + q15) * HDIM + 8 * g);

    f32x4 acc0 = {0.f, 0.f, 0.f, 0.f};
    f32x4 acc1 = {0.f, 0.f, 0.f, 0.f};
    float mrun = -INFINITY, lrun = 0.f;

    const int kkey = tid >> 2, kd0 = (tid & 3) * 8;
    const int vd   = tid >> 3, vk0 = (tid & 7) * 8;

    gl_lds16(kp + (size_t)kkey * HDIM + kd0, (void*)(&Kl[0][0] + tid * 8));
    gl_lds16(vtp + (size_t)vd * S_LEN + vk0, (void*)(&Vl[0][0] + tid * 8));
    __syncthreads();

    int cur = 0;
    for (int kt = 0; kt < 16; ++kt) {
        if (kt + 1 < 16) {
            const int kb2 = (kt + 1) * 64;
            gl_lds16(kp + (size_t)(kb2 + kkey) * HDIM + kd0,
                     (void*)(&Kl[cur ^ 1][0] + tid * 8));
            gl_lds16(vtp + (size_t)vd * S_LEN + kb2 + vk0,
                     (void*)(&Vl[cur ^ 1][0] + tid * 8));
        }
        __hip_bfloat16* Pw = &Pl[w][0];

        f32x4 sc[4];
        #pragma unroll
        for (int sub = 0; sub < 4; ++sub) {
            bf16x8 kf = *(const bf16x8*)(&Kl[cur][(sub * 16 + q15) * HDIM + 8 * g]);
            f32x4 z = {0.f, 0.f, 0.f, 0.f};
            sc[sub] = __builtin_amdgcn_mfma_f32_16x16x32_bf16(kf, qf, z, 0, 0, 0);
        }

        float tm = sc[0][0];
        #pragma unroll
        for (int sub = 0; sub < 4; ++sub)
            #pragma unroll
            for (int r = 0; r < 4; ++r) tm = fmaxf(tm, sc[sub][r]);
        tm = fmaxf(tm, __shfl_xor(tm, 16));
        tm = fmaxf(tm, __shfl_xor(tm, 32));
        const float mnew  = fmaxf(mrun, tm);
        const float alpha = __builtin_amdgcn_exp2f(mrun - mnew);
        float psum = 0.f;
        #pragma unroll
        for (int sub = 0; sub < 4; ++sub) {
            bf16x4 pk;
            #pragma unroll
            for (int r = 0; r < 4; ++r) {
                float p = __builtin_amdgcn_exp2f(sc[sub][r] - mnew);
                psum += p;
                pk[r] = (short)f2bf(p);
            }
            *(bf16x4*)(Pw + q15 * 72 + sub * 16 + 4 * g) = pk;
        }
        psum += __shfl_xor(psum, 16);
        psum += __shfl_xor(psum, 32);
        lrun = lrun * alpha + psum;
        mrun = mnew;

        const float a0 = __shfl(alpha, 4 * g + 0);
        const float a1 = __shfl(alpha, 4 * g + 1);
        const float a2 = __shfl(alpha, 4 * g + 2);
        const float a3 = __shfl(alpha, 4 * g + 3);
        acc0[0] *= a0; acc0[1] *= a1; acc0[2] *= a2; acc0[3] *= a3;
        acc1[0] *= a0; acc1[1] *= a1; acc1[2] *= a2; acc1[3] *= a3;

        #pragma unroll
        for (int kc = 0; kc < 2; ++kc) {
            bf16x8 pf = *(const bf16x8*)(Pw + q15 * 72 + kc * 32 + 8 * g);
            bf16x8 v0 = *(const bf16x8*)(&Vl[cur][q15 * 64 + kc * 32 + 8 * g]);
            bf16x8 v1 = *(const bf16x8*)(&Vl[cur][(16 + q15) * 64 + kc * 32 + 8 * g]);
            acc0 = __builtin_amdgcn_mfma_f32_16x16x32_bf16(pf, v0, acc0, 0, 0, 0);
            acc1 = __builtin_amdgcn_mfma_f32_16x16x32_bf16(pf, v1, acc1, 0, 0, 0);
        }

        __syncthreads();
        cur ^= 1;
    }

    const float inv = 1.f / lrun;
    float iv[4];
    iv[0] = __shfl(inv, 4 * g + 0);
    iv[1] = __shfl(inv, 4 * g + 1);
    iv[2] = __shfl(inv, 4 * g + 2);
    iv[3] = __shfl(inv, 4 * g + 3);
    const int b = bh >> 2, h = bh & 3;
    #pragma unroll
    for (int r = 0; r < 4; ++r) {
        const int srow = qt * 64 + w * 16 + 4 * g + r;
        __hip_bfloat16* ap = att + ((size_t)srow * BATCH + b) * EMB + h * HDIM;
        ap[q15]      = __float2bfloat16(acc0[r] * iv[r]);
        ap[16 + q15] = __float2bfloat16(acc1[r] * iv[r]);
    }
}

// ---------------- Kernel 3: out_proj MFMA + bias + residual + LayerNorm ----
// grid 512: 64 tokens x 128 f per block. 4 waves 2x2.
__global__ __launch_bounds__(256)
void proj_ln_mfma(const float* __restrict__ x,
                  const __hip_bfloat16* __restrict__ att,
                  const __hip_bfloat16* __restrict__ wobf,
                  const float* __restrict__ biasf,
                  const float* __restrict__ gm, const float* __restrict__ bt,
                  float* __restrict__ out)
{
    __shared__ __align__(16) unsigned char smem[32768 + 16384 + 1024];
    __hip_bfloat16* wl = (__hip_bfloat16*)smem;              // [128][128] XOR-swz
    __hip_bfloat16* al = (__hip_bfloat16*)(smem + 32768);    // [64][128] XOR-swz
    float* red = (float*)(smem + 32768 + 16384);             // [2][128]

    const int tid = threadIdx.x;
    const int t0  = blockIdx.x * 64;

    #pragma unroll
    for (int j = 0; j < 8; ++j) {
        int idx = tid + j * 256;
        int fl = idx >> 4, c = idx & 15;
        int cs = c ^ (fl & 15);
        gl_lds16(wobf + fl * 128 + cs * 8, wl + idx * 8);
    }
    #pragma unroll
    for (int j = 0; j < 4; ++j) {
        int idx = tid + j * 256;
        int fl = idx >> 4, c = idx & 15;
        int cs = c ^ (fl & 15);
        gl_lds16(att + (size_t)(t0 + fl) * 128 + cs * 8, al + idx * 8);
    }
    __syncthreads();

    const int wv = tid >> 6, wm = wv >> 1, wn = wv & 1;
    const int l = tid & 63, q15 = l & 15, g = l >> 4;

    bf16x8 af[2][4];
    #pragma unroll
    for (int tt = 0; tt < 2; ++tt)
        #pragma unroll
        for (int kc = 0; kc < 4; ++kc)
            af[tt][kc] = *(const bf16x8*)(al + (wm * 32 + tt * 16 + q15) * 128
                                          + (((kc * 4 + g) ^ q15) * 8));

    f32x4 acc[4][2];
    #pragma unroll
    for (int nt = 0; nt < 4; ++nt)
        #pragma unroll
        for (int tt = 0; tt < 2; ++tt)
            acc[nt][tt] = (f32x4){0.f, 0.f, 0.f, 0.f};

    #pragma unroll
    for (int nt = 0; nt < 4; ++nt) {
        const int fl = wn * 64 + nt * 16 + q15;
        #pragma unroll
        for (int kc = 0; kc < 4; ++kc) {
            bf16x8 wf = *(const bf16x8*)(wl + fl * 128
                                         + (((kc * 4 + g) ^ q15) * 8));
            acc[nt][0] = __builtin_amdgcn_mfma_f32_16x16x32_bf16(wf, af[0][kc], acc[nt][0], 0, 0, 0);
            acc[nt][1] = __builtin_amdgcn_mfma_f32_16x16x32_bf16(wf, af[1][kc], acc[nt][1], 0, 0, 0);
        }
    }

    // ---- bias + residual; per-token partial sums (f split across wn waves)
    float vv[4][2][4];
    float psum[2] = {0.f, 0.f}, psq[2] = {0.f, 0.f};
    #pragma unroll
    for (int nt = 0; nt < 4; ++nt) {
        const int f0 = wn * 64 + nt * 16 + 4 * g;
        float4 bv = *(const float4*)(biasf + 384 + f0);
        const float* bvp = (const float*)&bv;
        #pragma unroll
        for (int tt = 0; tt < 2; ++tt) {
            const int t = t0 + wm * 32 + tt * 16 + q15;
            float4 xv = *(const float4*)(x + (size_t)t * 128 + f0);
            const float* xvp = (const float*)&xv;
            #pragma unroll
            for (int r = 0; r < 4; ++r) {
                float v = acc[nt][tt][r] + bvp[r] + xvp[r];
                vv[nt][tt][r] = v;
                psum[tt] += v;
                psq[tt]  = fmaf(v, v, psq[tt]);
            }
        }
    }
    #pragma unroll
    for (int tt = 0; tt < 2; ++tt) {
        psum[tt] += __shfl_xor(psum[tt], 16);
        psum[tt] += __shfl_xor(psum[tt], 32);
        psq[tt]  += __shfl_xor(psq[tt], 16);
        psq[tt]  += __shfl_xor(psq[tt], 32);
    }
    if (l < 16) {
        #pragma unroll
        for (int tt = 0; tt < 2; ++tt) {
            int idx = ((wn * 2 + wm) * 2 + tt) * 16 + q15;
            red[idx]       = psum[tt];
            red[128 + idx] = psq[tt];
        }
    }
    __syncthreads();

    float mean[2], rstd[2];
    #pragma unroll
    for (int tt = 0; tt < 2; ++tt) {
        int oidx = (((wn ^ 1) * 2 + wm) * 2 + tt) * 16 + q15;
        float s  = psum[tt] + red[oidx];
        float sq = psq[tt]  + red[128 + oidx];
        mean[tt] = s * (1.f / 128.f);
        float var = sq * (1.f / 128.f) - mean[tt] * mean[tt];
        rstd[tt] = rsqrtf(var + 1e-5f);
    }

    #pragma unroll
    for (int nt = 0; nt < 4; ++nt) {
        const int f0 = wn * 64 + nt * 16 + 4 * g;
        float4 gv  = *(const float4*)(gm + f0);
        float4 btv = *(const float4*)(bt + f0);
        const float* gvp = (const float*)&gv;
        const float* btp = (const float*)&btv;
        #pragma unroll
        for (int tt = 0; tt < 2; ++tt) {
            const int t = t0 + wm * 32 + tt * 16 + q15;
            float4 o;
            float* op = (float*)&o;
            #pragma unroll
            for (int r = 0; r < 4; ++r)
                op[r] = (vv[nt][tt][r] - mean[tt]) * rstd[tt] * gvp[r] + btp[r];
            *(float4*)(out + (size_t)t * 128 + f0) = o;
        }
    }
}

extern "C" void kernel_launch(void* const* d_in, const int* in_sizes, int n_in,
                              void* d_out, int out_size, void* d_ws, size_t ws_size,
                              hipStream_t stream) {
    const float* x     = (const float*)d_in[0];
    const float* wi    = (const float*)d_in[1];
    const float* bi    = (const float*)d_in[2];
    const float* wo    = (const float*)d_in[3];
    const float* bo    = (const float*)d_in[4];
    const float* gamma = (const float*)d_in[5];
    const float* beta  = (const float*)d_in[6];
    float* out = (float*)d_out;

    unsigned char* wsb = (unsigned char*)d_ws;
    __hip_bfloat16* wbf   = (__hip_bfloat16*)wsb;               // 98304 B
    __hip_bfloat16* wobf  = (__hip_bfloat16*)(wsb + 98304);     // 32768 B
    float*          biasf = (float*)(wsb + 131072);             // 2048 B
    __hip_bfloat16* qb    = (__hip_bfloat16*)(wsb + 133120);    // 8 MB each
    __hip_bfloat16* kb    = qb + HBUF;
    __hip_bfloat16* vtb   = kb + HBUF;
    __hip_bfloat16* att   = vtb + HBUF;                          // 8 MB

    wcvt_kernel<<<65, 256, 0, stream>>>(wi, bi, wo, bo, wbf, wobf, biasf);
    qkv_mfma_kernel<<<dim3(512, 3), 256, 0, stream>>>(x, wbf, biasf, qb, kb, vtb);
    attn_kernel<<<dim3(BHN, 16), 256, 0, stream>>>(qb, kb, vtb, att);
    proj_ln_mfma<<<512, 256, 0, stream>>>(x, att, wobf, biasf, gamma, beta, out);
}

// Round 6
// 72.574 us; speedup vs baseline: 7.2627x; 1.2107x over previous
//
#include <hip/hip_runtime.h>
#include <hip/hip_bf16.h>
#include <math.h>

#define S_LEN 1024
#define BATCH 32
#define EMB   128
#define NHEAD 4
#define HDIM  32
#define BHN   (BATCH*NHEAD)          // 128
#define HBUF  (BHN*S_LEN*HDIM)       // 4194304 elements per q/k/v (bf16)
#define NTOK  (S_LEN*BATCH)          // 32768

typedef __attribute__((ext_vector_type(4))) float f32x4;
typedef __attribute__((ext_vector_type(8))) short bf16x8;
typedef __attribute__((ext_vector_type(4))) short bf16x4;
typedef __attribute__((ext_vector_type(2))) unsigned int u32x2;

// (1/sqrt(32)) * log2(e): folded into Wq/bq by wcvt_kernel
#define Q_PRESCALE 0.25503588f

__device__ __forceinline__ unsigned short f2bf(float f) {
    union { float f; unsigned u; } v; v.f = f;
    unsigned r = v.u + 0x7fff + ((v.u >> 16) & 1);   // RNE
    return (unsigned short)(r >> 16);
}

__device__ __forceinline__ float max3f(float a, float b, float c) {
    return fmaxf(fmaxf(a, b), c);    // fuses to v_max3_f32
}

__device__ __forceinline__ void gl_lds16(const void* g, void* l) {
    __builtin_amdgcn_global_load_lds(
        (const __attribute__((address_space(1))) unsigned*)g,
        (__attribute__((address_space(3))) unsigned*)l, 16, 0, 0);
}

// ---------------- Kernel 0: weight/bias convert (fp32 -> bf16) -------------
__global__ __launch_bounds__(256)
void wcvt_kernel(const float* __restrict__ w, const float* __restrict__ bias,
                 const float* __restrict__ wo, const float* __restrict__ bo,
                 __hip_bfloat16* __restrict__ wbf,
                 __hip_bfloat16* __restrict__ wobf,
                 float* __restrict__ biasf)
{
    const int bid = blockIdx.x, tid = threadIdx.x;
    if (bid < 48) {
        int e = bid * 1024 + tid * 4;
        float4 v = *(const float4*)(w + e);
        float s = (e < 128 * 128) ? Q_PRESCALE : 1.f;
        bf16x4 o;
        o[0] = (short)f2bf(v.x * s); o[1] = (short)f2bf(v.y * s);
        o[2] = (short)f2bf(v.z * s); o[3] = (short)f2bf(v.w * s);
        *(bf16x4*)(wbf + e) = o;
    } else if (bid < 64) {
        int e = (bid - 48) * 1024 + tid * 4;
        float4 v = *(const float4*)(wo + e);
        bf16x4 o;
        o[0] = (short)f2bf(v.x); o[1] = (short)f2bf(v.y);
        o[2] = (short)f2bf(v.z); o[3] = (short)f2bf(v.w);
        *(bf16x4*)(wobf + e) = o;
    } else if (tid < 96) {
        int e = tid * 4;
        float4 v = *(const float4*)(bias + e);
        float s = (e < 128) ? Q_PRESCALE : 1.f;
        v.x *= s; v.y *= s; v.z *= s; v.w *= s;
        *(float4*)(biasf + e) = v;
    } else if (tid < 128) {
        int e = (tid - 96) * 4;
        *(float4*)(biasf + 384 + e) = *(const float4*)(bo + e);
    }
}

// ---------------- Kernel 1: QKV projection, bf16 MFMA ----------------
__global__ __launch_bounds__(256)
void qkv_mfma_kernel(const float* __restrict__ x,
                     const __hip_bfloat16* __restrict__ wbf,
                     const float* __restrict__ biasf,
                     __hip_bfloat16* __restrict__ qb,
                     __hip_bfloat16* __restrict__ kb,
                     __hip_bfloat16* __restrict__ vtb)
{
    __shared__ __align__(16) unsigned char smem[17408 + 32768];
    __hip_bfloat16* xs = (__hip_bfloat16*)smem;            // [64][136] padded
    __hip_bfloat16* wl = (__hip_bfloat16*)(smem + 17408);  // [128][128] XOR-swz
    const int tid   = threadIdx.x;
    const int mt    = blockIdx.x;
    const int which = blockIdx.y;        // 0=q 1=k 2=v
    const int b0 = (mt & 7) * 4;
    const int s0 = (mt >> 3) * 16;

    const __hip_bfloat16* wsec = wbf + which * (128 * 128);
    #pragma unroll
    for (int j = 0; j < 8; ++j) {
        int idx = tid + j * 256;
        int fl = idx >> 4, c = idx & 15;
        int cs = c ^ (fl & 15);
        gl_lds16(wsec + fl * 128 + cs * 8, wl + idx * 8);
    }
    #pragma unroll
    for (int j = 0; j < 8; ++j) {
        int idx = tid + j * 256;
        int lt = idx >> 5, c4 = idx & 31;
        int t = (s0 + (lt & 15)) * 32 + b0 + (lt >> 4);
        float4 v = *(const float4*)(x + (size_t)t * 128 + c4 * 4);
        bf16x4 o;
        o[0] = (short)f2bf(v.x); o[1] = (short)f2bf(v.y);
        o[2] = (short)f2bf(v.z); o[3] = (short)f2bf(v.w);
        *(bf16x4*)(xs + lt * 136 + c4 * 4) = o;
    }
    __syncthreads();

    const int wv = tid >> 6, wm = wv >> 1, wn = wv & 1;
    const int l = tid & 63, q15 = l & 15, g = l >> 4;

    bf16x8 xf[2][4];
    #pragma unroll
    for (int tt = 0; tt < 2; ++tt)
        #pragma unroll
        for (int kc = 0; kc < 4; ++kc)
            xf[tt][kc] = *(const bf16x8*)(xs + (wm * 32 + tt * 16 + q15) * 136
                                          + kc * 32 + 8 * g);

    f32x4 acc[4][2];
    #pragma unroll
    for (int nt = 0; nt < 4; ++nt)
        #pragma unroll
        for (int tt = 0; tt < 2; ++tt)
            acc[nt][tt] = (f32x4){0.f, 0.f, 0.f, 0.f};

    #pragma unroll
    for (int nt = 0; nt < 4; ++nt) {
        const int fl = wn * 64 + nt * 16 + q15;
        #pragma unroll
        for (int kc = 0; kc < 4; ++kc) {
            bf16x8 wf = *(const bf16x8*)(wl + fl * 128
                                         + (((kc * 4 + g) ^ q15) * 8));
            acc[nt][0] = __builtin_amdgcn_mfma_f32_16x16x32_bf16(wf, xf[0][kc], acc[nt][0], 0, 0, 0);
            acc[nt][1] = __builtin_amdgcn_mfma_f32_16x16x32_bf16(wf, xf[1][kc], acc[nt][1], 0, 0, 0);
        }
    }
    __syncthreads();
    __hip_bfloat16* ol = wl;

    if (which < 2) {
        #pragma unroll
        for (int nt = 0; nt < 4; ++nt) {
            float4 bv = *(const float4*)(biasf + which * 128 + wn * 64 + nt * 16 + 4 * g);
            #pragma unroll
            for (int tt = 0; tt < 2; ++tt) {
                bf16x4 pk;
                pk[0] = (short)f2bf(acc[nt][tt][0] + bv.x);
                pk[1] = (short)f2bf(acc[nt][tt][1] + bv.y);
                pk[2] = (short)f2bf(acc[nt][tt][2] + bv.z);
                pk[3] = (short)f2bf(acc[nt][tt][3] + bv.w);
                *(bf16x4*)(ol + (wm * 32 + tt * 16 + q15) * 136
                           + wn * 64 + nt * 16 + 4 * g) = pk;
            }
        }
        __syncthreads();
        const int bb = tid >> 6, rr = tid & 63, ss = rr >> 2, c4 = rr & 3;
        __hip_bfloat16* dst = (which == 0) ? qb : kb;
        #pragma unroll
        for (int i = 0; i < 4; ++i) {
            bf16x8 vv = *(const bf16x8*)(ol + (bb * 16 + ss) * 136 + i * 32 + c4 * 8);
            *(bf16x8*)(dst + ((size_t)((b0 + bb) * 4 + i)) * 32768
                       + (s0 + ss) * 32 + c4 * 8) = vv;
        }
    } else {
        #pragma unroll
        for (int nt = 0; nt < 4; ++nt) {
            float4 bv = *(const float4*)(biasf + 256 + wn * 64 + nt * 16 + 4 * g);
            const float* bvp = (const float*)&bv;
            #pragma unroll
            for (int tt = 0; tt < 2; ++tt) {
                #pragma unroll
                for (int r = 0; r < 4; ++r) {
                    int f = wn * 64 + nt * 16 + 4 * g + r;
                    ol[f * 72 + wm * 32 + tt * 16 + q15] =
                        __float2bfloat16(acc[nt][tt][r] + bvp[r]);
                }
            }
        }
        __syncthreads();
        const int bb = tid >> 6, rr = tid & 63, fln = rr >> 1, sh = rr & 1;
        #pragma unroll
        for (int i = 0; i < 4; ++i) {
            int f = i * 32 + fln;
            bf16x8 vv = *(const bf16x8*)(ol + f * 72 + bb * 16 + sh * 8);
            *(bf16x8*)(vtb + ((size_t)((b0 + bb) * 4 + i)) * 32768
                       + (size_t)fln * 1024 + s0 + sh * 8) = vv;
        }
    }
}

// ---------------- Kernel 2: flash attention, bf16 MFMA ----------------
// V tile XOR-swizzled (granule ^= d&7); defer-max; v_perm P-pack.
__global__ __launch_bounds__(256)
void attn_kernel(const __hip_bfloat16* __restrict__ qg,
                 const __hip_bfloat16* __restrict__ kg,
                 const __hip_bfloat16* __restrict__ vtg,
                 __hip_bfloat16* __restrict__ att)
{
    __shared__ __hip_bfloat16 Kl[2][64 * 32];
    __shared__ __hip_bfloat16 Vl[2][32 * 64];
    __shared__ __hip_bfloat16 Pl[4][16 * 72];

    const int tid = threadIdx.x;
    const int w   = tid >> 6;
    const int l   = tid & 63;
    const int q15 = l & 15;
    const int g   = l >> 4;
    const int bh  = blockIdx.x;
    const int qt  = blockIdx.y;

    const __hip_bfloat16* kp  = kg  + (size_t)bh * (S_LEN * HDIM);
    const __hip_bfloat16* vtp = vtg + (size_t)bh * (HDIM * S_LEN);

    bf16x8 qf = *(const bf16x8*)(qg + (size_t)bh * (S_LEN * HDIM)
                                 + (size_t)(qt * 64 + w * 16 + q15) * HDIM + 8 * g);

    f32x4 acc0 = {0.f, 0.f, 0.f, 0.f};
    f32x4 acc1 = {0.f, 0.f, 0.f, 0.f};
    float mrun = -INFINITY, lrun = 0.f;

    const int kkey = tid >> 2, kd0 = (tid & 3) * 8;
    // V staging: LDS granule (tid&7) of row (tid>>3) holds global granule
    // (tid&7)^(row&7)  -> read side applies the same XOR (bank-even reads)
    const int vd = tid >> 3, vg0 = ((tid & 7) ^ (vd & 7)) * 8;
    const int vswz = (q15 & 7);          // read-side XOR for rows q15, q15+16

    gl_lds16(kp + (size_t)kkey * HDIM + kd0, (void*)(&Kl[0][0] + tid * 8));
    gl_lds16(vtp + (size_t)vd * S_LEN + vg0, (void*)(&Vl[0][0] + tid * 8));
    __syncthreads();

    int cur = 0;
    for (int kt = 0; kt < 16; ++kt) {
        if (kt + 1 < 16) {
            const int kb2 = (kt + 1) * 64;
            gl_lds16(kp + (size_t)(kb2 + kkey) * HDIM + kd0,
                     (void*)(&Kl[cur ^ 1][0] + tid * 8));
            gl_lds16(vtp + (size_t)vd * S_LEN + kb2 + vg0,
                     (void*)(&Vl[cur ^ 1][0] + tid * 8));
        }
        __hip_bfloat16* Pw = &Pl[w][0];

        // ---- QK^T: 4 MFMAs
        f32x4 sc[4];
        #pragma unroll
        for (int sub = 0; sub < 4; ++sub) {
            bf16x8 kf = *(const bf16x8*)(&Kl[cur][(sub * 16 + q15) * HDIM + 8 * g]);
            f32x4 z = {0.f, 0.f, 0.f, 0.f};
            sc[sub] = __builtin_amdgcn_mfma_f32_16x16x32_bf16(kf, qf, z, 0, 0, 0);
        }

        // ---- per-lane tile max (max3 tree)
        float tm16 = max3f(sc[0][0], sc[0][1], sc[0][2]);
        tm16 = max3f(tm16, sc[0][3], sc[1][0]);
        tm16 = max3f(tm16, sc[1][1], sc[1][2]);
        tm16 = max3f(tm16, sc[1][3], sc[2][0]);
        tm16 = max3f(tm16, sc[2][1], sc[2][2]);
        tm16 = max3f(tm16, sc[2][3], sc[3][0]);
        tm16 = max3f(tm16, sc[3][1], sc[3][2]);
        tm16 = fmaxf(tm16, sc[3][3]);

        // ---- defer-max: rescale only when max grew past THR=8 (log2 units)
        if (!__all(tm16 <= mrun + 8.f)) {
            float tm = fmaxf(tm16, __shfl_xor(tm16, 16));
            tm = fmaxf(tm, __shfl_xor(tm, 32));
            const float mnew  = fmaxf(mrun, tm);
            const float alpha = __builtin_amdgcn_exp2f(mrun - mnew);
            const float a0 = __shfl(alpha, 4 * g + 0);
            const float a1 = __shfl(alpha, 4 * g + 1);
            const float a2 = __shfl(alpha, 4 * g + 2);
            const float a3 = __shfl(alpha, 4 * g + 3);
            acc0[0] *= a0; acc0[1] *= a1; acc0[2] *= a2; acc0[3] *= a3;
            acc1[0] *= a0; acc1[1] *= a1; acc1[2] *= a2; acc1[3] *= a3;
            lrun *= alpha;
            mrun = mnew;
        }

        // ---- P = exp2(sc - mrun); pack to bf16 via v_perm (truncate)
        float psum = 0.f;
        #pragma unroll
        for (int sub = 0; sub < 4; ++sub) {
            float p0 = __builtin_amdgcn_exp2f(sc[sub][0] - mrun);
            float p1 = __builtin_amdgcn_exp2f(sc[sub][1] - mrun);
            float p2 = __builtin_amdgcn_exp2f(sc[sub][2] - mrun);
            float p3 = __builtin_amdgcn_exp2f(sc[sub][3] - mrun);
            psum += (p0 + p1) + (p2 + p3);
            u32x2 pk;
            pk[0] = __builtin_amdgcn_perm(__float_as_uint(p1),
                                          __float_as_uint(p0), 0x07060302u);
            pk[1] = __builtin_amdgcn_perm(__float_as_uint(p3),
                                          __float_as_uint(p2), 0x07060302u);
            *(u32x2*)(Pw + q15 * 72 + sub * 16 + 4 * g) = pk;
        }
        psum += __shfl_xor(psum, 16);
        psum += __shfl_xor(psum, 32);
        lrun += psum;

        // ---- PV: P (A) x Vt (B), swizzled V reads
        #pragma unroll
        for (int kc = 0; kc < 2; ++kc) {
            bf16x8 pf = *(const bf16x8*)(Pw + q15 * 72 + kc * 32 + 8 * g);
            const int gs = ((kc * 4 + g) ^ vswz) * 8;
            bf16x8 v0 = *(const bf16x8*)(&Vl[cur][q15 * 64 + gs]);
            bf16x8 v1 = *(const bf16x8*)(&Vl[cur][(16 + q15) * 64 + gs]);
            acc0 = __builtin_amdgcn_mfma_f32_16x16x32_bf16(pf, v0, acc0, 0, 0, 0);
            acc1 = __builtin_amdgcn_mfma_f32_16x16x32_bf16(pf, v1, acc1, 0, 0, 0);
        }

        __syncthreads();
        cur ^= 1;
    }

    const float inv = 1.f / lrun;
    float iv[4];
    iv[0] = __shfl(inv, 4 * g + 0);
    iv[1] = __shfl(inv, 4 * g + 1);
    iv[2] = __shfl(inv, 4 * g + 2);
    iv[3] = __shfl(inv, 4 * g + 3);
    const int b = bh >> 2, h = bh & 3;
    #pragma unroll
    for (int r = 0; r < 4; ++r) {
        const int srow = qt * 64 + w * 16 + 4 * g + r;
        __hip_bfloat16* ap = att + ((size_t)srow * BATCH + b) * EMB + h * HDIM;
        ap[q15]      = __float2bfloat16(acc0[r] * iv[r]);
        ap[16 + q15] = __float2bfloat16(acc1[r] * iv[r]);
    }
}

// ---------------- Kernel 3: out_proj MFMA + bias + residual + LayerNorm ----
__global__ __launch_bounds__(256)
void proj_ln_mfma(const float* __restrict__ x,
                  const __hip_bfloat16* __restrict__ att,
                  const __hip_bfloat16* __restrict__ wobf,
                  const float* __restrict__ biasf,
                  const float* __restrict__ gm, const float* __restrict__ bt,
                  float* __restrict__ out)
{
    __shared__ __align__(16) unsigned char smem[32768 + 16384 + 1024];
    __hip_bfloat16* wl = (__hip_bfloat16*)smem;              // [128][128] XOR-swz
    __hip_bfloat16* al = (__hip_bfloat16*)(smem + 32768);    // [64][128] XOR-swz
    float* red = (float*)(smem + 32768 + 16384);             // [2][128]

    const int tid = threadIdx.x;
    const int t0  = blockIdx.x * 64;

    #pragma unroll
    for (int j = 0; j < 8; ++j) {
        int idx = tid + j * 256;
        int fl = idx >> 4, c = idx & 15;
        int cs = c ^ (fl & 15);
        gl_lds16(wobf + fl * 128 + cs * 8, wl + idx * 8);
    }
    #pragma unroll
    for (int j = 0; j < 4; ++j) {
        int idx = tid + j * 256;
        int fl = idx >> 4, c = idx & 15;
        int cs = c ^ (fl & 15);
        gl_lds16(att + (size_t)(t0 + fl) * 128 + cs * 8, al + idx * 8);
    }
    __syncthreads();

    const int wv = tid >> 6, wm = wv >> 1, wn = wv & 1;
    const int l = tid & 63, q15 = l & 15, g = l >> 4;

    bf16x8 af[2][4];
    #pragma unroll
    for (int tt = 0; tt < 2; ++tt)
        #pragma unroll
        for (int kc = 0; kc < 4; ++kc)
            af[tt][kc] = *(const bf16x8*)(al + (wm * 32 + tt * 16 + q15) * 128
                                          + (((kc * 4 + g) ^ q15) * 8));

    f32x4 acc[4][2];
    #pragma unroll
    for (int nt = 0; nt < 4; ++nt)
        #pragma unroll
        for (int tt = 0; tt < 2; ++tt)
            acc[nt][tt] = (f32x4){0.f, 0.f, 0.f, 0.f};

    #pragma unroll
    for (int nt = 0; nt < 4; ++nt) {
        const int fl = wn * 64 + nt * 16 + q15;
        #pragma unroll
        for (int kc = 0; kc < 4; ++kc) {
            bf16x8 wf = *(const bf16x8*)(wl + fl * 128
                                         + (((kc * 4 + g) ^ q15) * 8));
            acc[nt][0] = __builtin_amdgcn_mfma_f32_16x16x32_bf16(wf, af[0][kc], acc[nt][0], 0, 0, 0);
            acc[nt][1] = __builtin_amdgcn_mfma_f32_16x16x32_bf16(wf, af[1][kc], acc[nt][1], 0, 0, 0);
        }
    }

    float vv[4][2][4];
    float psum[2] = {0.f, 0.f}, psq[2] = {0.f, 0.f};
    #pragma unroll
    for (int nt = 0; nt < 4; ++nt) {
        const int f0 = wn * 64 + nt * 16 + 4 * g;
        float4 bv = *(const float4*)(biasf + 384 + f0);
        const float* bvp = (const float*)&bv;
        #pragma unroll
        for (int tt = 0; tt < 2; ++tt) {
            const int t = t0 + wm * 32 + tt * 16 + q15;
            float4 xv = *(const float4*)(x + (size_t)t * 128 + f0);
            const float* xvp = (const float*)&xv;
            #pragma unroll
            for (int r = 0; r < 4; ++r) {
                float v = acc[nt][tt][r] + bvp[r] + xvp[r];
                vv[nt][tt][r] = v;
                psum[tt] += v;
                psq[tt]  = fmaf(v, v, psq[tt]);
            }
        }
    }
    #pragma unroll
    for (int tt = 0; tt < 2; ++tt) {
        psum[tt] += __shfl_xor(psum[tt], 16);
        psum[tt] += __shfl_xor(psum[tt], 32);
        psq[tt]  += __shfl_xor(psq[tt], 16);
        psq[tt]  += __shfl_xor(psq[tt], 32);
    }
    if (l < 16) {
        #pragma unroll
        for (int tt = 0; tt < 2; ++tt) {
            int idx = ((wn * 2 + wm) * 2 + tt) * 16 + q15;
            red[idx]       = psum[tt];
            red[128 + idx] = psq[tt];
        }
    }
    __syncthreads();

    float mean[2], rstd[2];
    #pragma unroll
    for (int tt = 0; tt < 2; ++tt) {
        int oidx = (((wn ^ 1) * 2 + wm) * 2 + tt) * 16 + q15;
        float s  = psum[tt] + red[oidx];
        float sq = psq[tt]  + red[128 + oidx];
        mean[tt] = s * (1.f / 128.f);
        float var = sq * (1.f / 128.f) - mean[tt] * mean[tt];
        rstd[tt] = rsqrtf(var + 1e-5f);
    }

    #pragma unroll
    for (int nt = 0; nt < 4; ++nt) {
        const int f0 = wn * 64 + nt * 16 + 4 * g;
        float4 gv  = *(const float4*)(gm + f0);
        float4 btv = *(const float4*)(bt + f0);
        const float* gvp = (const float*)&gv;
        const float* btp = (const float*)&btv;
        #pragma unroll
        for (int tt = 0; tt < 2; ++tt) {
            const int t = t0 + wm * 32 + tt * 16 + q15;
            float4 o;
            float* op = (float*)&o;
            #pragma unroll
            for (int r = 0; r < 4; ++r)
                op[r] = (vv[nt][tt][r] - mean[tt]) * rstd[tt] * gvp[r] + btp[r];
            *(float4*)(out + (size_t)t * 128 + f0) = o;
        }
    }
}

extern "C" void kernel_launch(void* const* d_in, const int* in_sizes, int n_in,
                              void* d_out, int out_size, void* d_ws, size_t ws_size,
                              hipStream_t stream) {
    const float* x     = (const float*)d_in[0];
    const float* wi    = (const float*)d_in[1];
    const float* bi    = (const float*)d_in[2];
    const float* wo    = (const float*)d_in[3];
    const float* bo    = (const float*)d_in[4];
    const float* gamma = (const float*)d_in[5];
    const float* beta  = (const float*)d_in[6];
    float* out = (float*)d_out;

    unsigned char* wsb = (unsigned char*)d_ws;
    __hip_bfloat16* wbf   = (__hip_bfloat16*)wsb;               // 98304 B
    __hip_bfloat16* wobf  = (__hip_bfloat16*)(wsb + 98304);     // 32768 B
    float*          biasf = (float*)(wsb + 131072);             // 2048 B
    __hip_bfloat16* qb    = (__hip_bfloat16*)(wsb + 133120);    // 8 MB each
    __hip_bfloat16* kb    = qb + HBUF;
    __hip_bfloat16* vtb   = kb + HBUF;
    __hip_bfloat16* att   = vtb + HBUF;                          // 8 MB

    wcvt_kernel<<<65, 256, 0, stream>>>(wi, bi, wo, bo, wbf, wobf, biasf);
    qkv_mfma_kernel<<<dim3(512, 3), 256, 0, stream>>>(x, wbf, biasf, qb, kb, vtb);
    attn_kernel<<<dim3(BHN, 16), 256, 0, stream>>>(qb, kb, vtb, att);
    proj_ln_mfma<<<512, 256, 0, stream>>>(x, att, wobf, biasf, gamma, beta, out);
}